// Round 9
// baseline (202.379 us; speedup 1.0000x reference)
//
#include <hip/hip_runtime.h>
#include <cstdint>
#include <cstddef>

#define LQ   2048
#define BQ   4
#define EQ   1024
#define HQ   8
#define D1Q  2048
#define HDQ  256
#define NBQ  (LQ*BQ)   // 8192 rows in (n,b) layout

typedef __bf16 bf16_t;
typedef __bf16 bf16x8 __attribute__((ext_vector_type(8)));
typedef __bf16 bf16x4 __attribute__((ext_vector_type(4)));
typedef float  f32x4  __attribute__((ext_vector_type(4)));

#define GAS1(p) ((const __attribute__((address_space(1))) void*)(p))
#define LAS3(p) ((__attribute__((address_space(3))) void*)(p))

// ---------------------------------------------------------------- utilities

__global__ __launch_bounds__(256) void convert_kernel(
    const float* __restrict__ Wu, const float* __restrict__ Wv,
    const float* __restrict__ Wo,
    bf16_t* __restrict__ Wub, bf16_t* __restrict__ Wvb,
    bf16_t* __restrict__ Wob)
{
    const size_t i = (size_t)blockIdx.x * 256 + threadIdx.x;
    if (i < (size_t)D1Q * EQ) {
        Wub[i] = (bf16_t)Wu[i];
        Wvb[i] = (bf16_t)Wv[i];
        Wob[i] = (bf16_t)Wo[i];
    }
}

// Precompute Toeplitz A-tiles, 128 rows x 64 cols (BK=64), diag offset (q-1)*64.
__global__ __launch_bounds__(256) void build_toep_tiles2(
    const float* __restrict__ zero, const float* __restrict__ pos,
    bf16_t* __restrict__ At)
{
    const int q = blockIdx.x;        // 0..31
    const int h = blockIdx.y;        // 0..7
    const int doff = (q - 1) * 64;
    const int tid = threadIdx.x;
    bf16_t* dst = At + ((size_t)h * 32 + q) * 8192;
    const int r  = tid >> 1;
    const int c0 = (tid & 1) * 32;
    bf16_t vals[32];
    #pragma unroll
    for (int j = 0; j < 32; ++j) {
        const int d = doff + r - (c0 + j);
        float v = 0.f;
        if (d == 0) v = zero[h];
        else if (d > 0 && d < LQ) v = pos[(size_t)h * (LQ - 1) + d - 1];
        vals[j] = (bf16_t)v;
    }
    #pragma unroll
    for (int qq = 0; qq < 4; ++qq)
        *(bf16x8*)(dst + r * 64 + c0 + qq * 8) = *(bf16x8*)(vals + qq * 8);
}

__global__ __launch_bounds__(256) void rmsnorm_kernel(
    const float* __restrict__ x, bf16_t* __restrict__ xn)
{
    const int row = blockIdx.x;           // 0..8191
    const int tid = threadIdx.x;
    const float4 v = ((const float4*)(x + (size_t)row * EQ))[tid];
    float ss = v.x*v.x + v.y*v.y + v.z*v.z + v.w*v.w;
    #pragma unroll
    for (int m = 32; m >= 1; m >>= 1) ss += __shfl_xor(ss, m, 64);
    __shared__ float red[4];
    const int wid = tid >> 6, lane = tid & 63;
    if (lane == 0) red[wid] = ss;
    __syncthreads();
    const float tot = red[0] + red[1] + red[2] + red[3];
    const float inv = 1.f / (sqrtf(tot * (1.f / EQ)) + 1e-8f);
    bf16x4 o;
    o[0] = (bf16_t)(v.x * inv); o[1] = (bf16_t)(v.y * inv);
    o[2] = (bf16_t)(v.z * inv); o[3] = (bf16_t)(v.w * inv);
    *(bf16x4*)(xn + (size_t)row * EQ + tid * 4) = o;
}

// ---------------------------------------------------------------- merged U+V GEMM
// 1024 threads = 16 waves (4M x 4N), wave tile 64x64, acc[4][4].
// BM=BN=256, BK=32; 4 LDS buffers x 32KB (128 KB); stage tile t+3 during tile t;
// ONE barrier per tile; counted vmcnt(4) boundary (never 0 until tail).
// B = [Wu; Wv] (4096 rows).  bx<8 -> U (silu, row-major); bx>=8 -> V (silu,
// (h,b,hd,t) via pair-wave LDS transpose, full 64-B t-runs).
__global__ __launch_bounds__(1024, 1) void gemm_uv(
    const bf16_t* __restrict__ A, const bf16_t* __restrict__ Bm,
    const float* __restrict__ bbu, const float* __restrict__ bbv,
    bf16_t* __restrict__ Ub, bf16_t* __restrict__ Vt)
{
    constexpr int K = EQ;            // 1024
    constexpr int BSTRIDE = 32768;   // A 16K + B 16K
    __shared__ alignas(16) char smem[4 * BSTRIDE];   // 128 KB

    // XCD-chunked bijective swizzle (nwg = 512)
    const int nwg  = gridDim.x * gridDim.y;
    const int bid0 = blockIdx.y * gridDim.x + blockIdx.x;
    const int chunkw = nwg >> 3;
    const int sb   = (bid0 & 7) * chunkw + (bid0 >> 3);
    const int bx   = sb % gridDim.x;
    const int by   = sb / gridDim.x;

    const int tid  = threadIdx.x;
    const int wid  = tid >> 6;          // 0..15
    const int lane = tid & 63;
    const int frow = lane & 15;
    const int c    = lane >> 4;
    const int m0 = by * 256;
    const int n0 = bx * 256;
    const int wrm = (wid >> 2) * 64;
    const int wrn = (wid & 3) * 64;

    // conflict-free swizzle (verified R7/R8: SQ_LDS_BANK_CONFLICT = 0)
    const int g = (frow >> 1) & 3;
    const int offA0 = (wrm + frow) * 64 + ((c ^ g) << 4);
    const int offB0 = 16384 + (wrn + frow) * 64 + ((c ^ g) << 4);

    const int rA   = tid >> 2;          // 0..255
    const int soff = (((tid & 3) ^ ((rA >> 1) & 3)) << 4);
    const size_t lda2 = (size_t)K * 2;
    const char* sA = (const char*)A  + (size_t)(m0 + rA) * lda2 + soff;
    const char* sB = (const char*)Bm + (size_t)(n0 + rA) * lda2 + soff;

    auto STAGE = [&](int bf, int kt) {
        char* d = smem + bf * BSTRIDE + wid * 1024;
        __builtin_amdgcn_global_load_lds(GAS1(sA + (size_t)kt * 64), LAS3(d), 16, 0, 0);
        __builtin_amdgcn_global_load_lds(GAS1(sB + (size_t)kt * 64), LAS3(d + 16384), 16, 0, 0);
    };

    f32x4 acc[4][4];
    #pragma unroll
    for (int i = 0; i < 4; ++i)
        #pragma unroll
        for (int j = 0; j < 4; ++j) acc[i][j] = (f32x4){0.f, 0.f, 0.f, 0.f};

    const int NT = K >> 5;              // 32

    STAGE(0, 0); STAGE(1, 1); STAGE(2, 2);
    asm volatile("s_waitcnt vmcnt(4)" ::: "memory");   // tile0 resident
    __builtin_amdgcn_s_barrier();

    for (int t = 0; t < NT; ++t) {
        const char* base = smem + (t & 3) * BSTRIDE;
        bf16x8 av[4], bfr[4];
        #pragma unroll
        for (int i = 0; i < 4; ++i) {
            av[i]  = *(const bf16x8*)(base + offA0 + i * 1024);
            bfr[i] = *(const bf16x8*)(base + offB0 + i * 1024);
        }
        if (t + 3 < NT) STAGE((t + 3) & 3, t + 3);
        __builtin_amdgcn_s_setprio(1);
        #pragma unroll
        for (int mi = 0; mi < 4; ++mi)
            #pragma unroll
            for (int ni = 0; ni < 4; ++ni)
                acc[mi][ni] = __builtin_amdgcn_mfma_f32_16x16x32_bf16(
                    av[mi], bfr[ni], acc[mi][ni], 0, 0, 0);
        __builtin_amdgcn_s_setprio(0);
        if (t + 3 < NT)      asm volatile("s_waitcnt vmcnt(4)" ::: "memory");
        else if (t + 2 < NT) asm volatile("s_waitcnt vmcnt(2)" ::: "memory");
        else if (t + 1 < NT) asm volatile("s_waitcnt vmcnt(0)" ::: "memory");
        if (t + 1 < NT) __builtin_amdgcn_s_barrier();
    }

    if (bx < 8) {
        // U epilogue: silu(acc + bu) -> row-major (nb, d1)
        const int fq = c * 4;
        #pragma unroll
        for (int mi = 0; mi < 4; ++mi) {
            #pragma unroll
            for (int ni = 0; ni < 4; ++ni) {
                const int gn = n0 + wrn + ni * 16 + frow;
                #pragma unroll
                for (int j = 0; j < 4; ++j) {
                    const int gm = m0 + wrm + mi * 16 + fq + j;
                    float v = acc[mi][ni][j] + bbu[gn];
                    v = v / (1.f + __expf(-v));
                    Ub[(size_t)gm * D1Q + gn] = (bf16_t)v;
                }
            }
        }
        return;
    }

    // V epilogue: silu(acc + bv) -> (h, b, hd, t), pair-wave LDS transpose.
    // Pair = waves (w, w+4) within a pass (pass = wid>>3): share chunk pi = wid&3,
    // member q = (wid>>2)&1 owns t-half q*16.  Chunk: [nl:64][b:4][t:32], stride
    // 132 elems (264 B -> read-back 2-per-bank max).  Store = full 64-B t-run.
    {
        const int n0v = n0 - 2048;
        const int hh  = n0v >> 8;
        float bb[4];
        #pragma unroll
        for (int ni = 0; ni < 4; ++ni) bb[ni] = bbv[n0v + wrn + ni * 16 + frow];

        const int pi   = wid & 3;
        const int q    = (wid >> 2) & 1;
        const int pass = wid >> 3;
        bf16_t* chunk = (bf16_t*)smem + pi * 8448;   // 64*132 elems = 16896 B

        #pragma unroll
        for (int p = 0; p < 2; ++p) {
            __syncthreads();
            if (pass == p) {
                #pragma unroll
                for (int mi = 0; mi < 4; ++mi)
                    #pragma unroll
                    for (int ni = 0; ni < 4; ++ni) {
                        const int nl = ni * 16 + frow;
                        #pragma unroll
                        for (int j = 0; j < 4; ++j) {   // j == b
                            float v = acc[mi][ni][j] + bb[ni];
                            v = v / (1.f + __expf(-v));
                            chunk[nl * 132 + j * 32 + q * 16 + mi * 4 + c] = (bf16_t)v;
                        }
                    }
            }
            __syncthreads();
            if (pass == p) {
                const int hd = wrn + lane;              // lane owns one hd row
                const int t0 = (m0 >> 2) + p * 32;      // pair covers 32 t (64 B)
                #pragma unroll
                for (int bi = 0; bi < 2; ++bi) {
                    const int b2 = q * 2 + bi;
                    const bf16_t* src = chunk + lane * 132 + b2 * 32;
                    bf16_t* dst = Vt + (((size_t)hh * 4 + b2) * 256 + hd) * (size_t)LQ + t0;
                    #pragma unroll
                    for (int u = 0; u < 4; ++u)
                        *(bf16x8*)(dst + u * 8) = *(const bf16x8*)(src + u * 8);
                }
            }
        }
    }
}

// ---------------------------------------------------------------- phase primitive
template<int KK, int MH, int WAITN, bool LDB, int MI_, typename F>
__device__ __forceinline__ void phase_op(const char* base, int offA0, int offB0,
    bf16x8 (&bv)[4], f32x4 (&acc)[MI_][4], F&& stage)
{
    bf16x8 av[4];
    #pragma unroll
    for (int i = 0; i < 4; ++i)
        av[i] = *(const bf16x8*)(base + (offA0 ^ (KK << 6)) + (MH * 4 + i) * 2048);
    if constexpr (LDB) {
        #pragma unroll
        for (int i = 0; i < 4; ++i)
            bv[i] = *(const bf16x8*)(base + (offB0 ^ (KK << 6)) + i * 2048);
    }
    stage();
    __builtin_amdgcn_s_barrier();
    __builtin_amdgcn_s_setprio(1);
    #pragma unroll
    for (int i = 0; i < 4; ++i)
        #pragma unroll
        for (int ni = 0; ni < 4; ++ni)
            acc[MH * 4 + i][ni] = __builtin_amdgcn_mfma_f32_16x16x32_bf16(
                av[i], bv[ni], acc[MH * 4 + i][ni], 0, 0, 0);
    __builtin_amdgcn_s_setprio(0);
    if constexpr (WAITN >= 0)
        asm volatile("s_waitcnt vmcnt(%0)" :: "i"(WAITN) : "memory");
    __builtin_amdgcn_s_barrier();
}

// ---------------------------------------------------------------- 4-phase 128x256 GEMM (final)
__global__ __launch_bounds__(512, 1) void gemm_fin(
    const bf16_t* __restrict__ A, const bf16_t* __restrict__ Bm,
    const float* __restrict__ bias, const float* __restrict__ res,
    float* __restrict__ Cf)
{
    constexpr int K = D1Q, N = EQ;
    constexpr int BSTRIDE = 49152;            // A 16K + B 32K
    __shared__ alignas(16) char smem[3 * BSTRIDE];

    const int nwg   = gridDim.x * gridDim.y;
    const int bid0  = blockIdx.y * gridDim.x + blockIdx.x;
    const int chunkw = nwg >> 3;
    const int sb    = (bid0 & 7) * chunkw + (bid0 >> 3);
    const int bx    = sb % gridDim.x;
    const int by    = sb / gridDim.x;

    const int tid  = threadIdx.x;
    const int wid  = tid >> 6;
    const int lane = tid & 63;
    const int frow = lane & 15;
    const int c    = lane >> 4;
    const int m0 = by * 128;
    const int n0 = bx * 256;
    const int wrm = (wid >> 2) * 64;
    const int wrn = (wid & 3) * 64;

    const int g = frow & 7;
    const int offA0 = (wrm + frow) * 128 + ((c ^ g) << 4);
    const int offB0 = 16384 + (wrn + frow) * 128 + ((c ^ g) << 4);

    const int rl = tid >> 3;
    const int ls = (tid & 7) ^ (rl & 7);
    const size_t lda2 = (size_t)K * 2;
    const char* sA = (const char*)A  + (size_t)(m0 + rl) * lda2 + ls * 16;
    const char* sB = (const char*)Bm + (size_t)(n0 + rl) * lda2 + ls * 16;

    auto SH_A = [&](int bf, int kt) {
        const char* s = sA + (size_t)kt * 128;
        char* d = smem + bf * BSTRIDE + wid * 1024;
        __builtin_amdgcn_global_load_lds(GAS1(s), LAS3(d), 16, 0, 0);
        __builtin_amdgcn_global_load_lds(GAS1(s + 64 * lda2), LAS3(d + 8192), 16, 0, 0);
    };
    auto SH_B = [&](int bf, int hf, int kt) {
        const char* s = sB + (size_t)(hf * 128) * lda2 + (size_t)kt * 128;
        char* d = smem + bf * BSTRIDE + 16384 + hf * 16384 + wid * 1024;
        __builtin_amdgcn_global_load_lds(GAS1(s), LAS3(d), 16, 0, 0);
        __builtin_amdgcn_global_load_lds(GAS1(s + 64 * lda2), LAS3(d + 8192), 16, 0, 0);
    };

    f32x4 acc[4][4];
    #pragma unroll
    for (int i = 0; i < 4; ++i)
        #pragma unroll
        for (int j = 0; j < 4; ++j) acc[i][j] = (f32x4){0.f, 0.f, 0.f, 0.f};
    bf16x8 bv[4];

    const int NT = K >> 6;                    // 32

    SH_A(0, 0); SH_B(0, 0, 0); SH_B(0, 1, 0);
    SH_A(1, 1); SH_B(1, 0, 1); SH_B(1, 1, 1);
    asm volatile("s_waitcnt vmcnt(6)" ::: "memory");
    __builtin_amdgcn_s_barrier();

    int cur = 0, pb = 2;
    for (int t = 0; t < NT; ++t) {
        const char* base = smem + cur * BSTRIDE;
        const int t2 = t + 2;
        const bool pf = t2 < NT;
        phase_op<0,0,-1,true>(base, offA0, offB0, bv, acc,
            [&]{ if (pf) { SH_A(pb, t2); SH_B(pb, 0, t2); } });
        phase_op<1,0, 6,true>(base, offA0, offB0, bv, acc,
            [&]{ if (pf) SH_B(pb, 1, t2); });
        cur = (cur == 2) ? 0 : cur + 1;
        pb  = (pb  == 2) ? 0 : pb  + 1;
    }

    const int fq = c * 4;
    #pragma unroll
    for (int mi = 0; mi < 4; ++mi) {
        #pragma unroll
        for (int ni = 0; ni < 4; ++ni) {
            const int gn = n0 + wrn + ni * 16 + frow;
            #pragma unroll
            for (int j = 0; j < 4; ++j) {
                const int gm = m0 + wrm + mi * 16 + fq + j;
                Cf[(size_t)gm * N + gn] =
                    acc[mi][ni][j] + bias[gn] + res[(size_t)gm * N + gn];
            }
        }
    }
}

// ---------------------------------------------------------------- 4-phase Toeplitz GEMM
__global__ __launch_bounds__(512, 1) void gemm_toep4p(
    const bf16_t* __restrict__ VT, const bf16_t* __restrict__ Atl,
    const bf16_t* __restrict__ U, bf16_t* __restrict__ O)
{
    constexpr int BSTRIDE = 49152;
    __shared__ alignas(16) char smem[3 * BSTRIDE];

    const int bid   = blockIdx.x;          // 0..511
    const int m_blk = 15 - (bid >> 5);     // heavy-first
    const int sub   = bid & 31;
    const int h     = sub >> 2;
    const int n0    = (sub & 3) * 256;
    const int m0    = m_blk * 128;

    const int tid  = threadIdx.x;
    const int wid  = tid >> 6;
    const int lane = tid & 63;
    const int frow = lane & 15;
    const int c    = lane >> 4;
    const int wrm  = (wid >> 2) * 64;
    const int wrn  = (wid & 3) * 64;

    const int g = frow & 7;
    const int offA0 = (wrm + frow) * 128 + ((c ^ g) << 4);
    const int offB0 = 16384 + (wrn + frow) * 128 + ((c ^ g) << 4);

    const int rl = tid >> 3;
    const int ls = (tid & 7) ^ (rl & 7);
    const char* Ah = (const char*)Atl + (size_t)h * 32 * 16384;
    const size_t ldb = (size_t)LQ * 2;
    const char* sB = (const char*)VT + ((size_t)h * 1024 + n0 + rl) * ldb + ls * 16;

    auto SH_A = [&](int bf, int kt) {
        const int q = 2 * m_blk - kt + 1;
        const char* s = Ah + (size_t)q * 16384 + (size_t)rl * 128 + ls * 16;
        char* d = smem + bf * BSTRIDE + wid * 1024;
        __builtin_amdgcn_global_load_lds(GAS1(s), LAS3(d), 16, 0, 0);
        __builtin_amdgcn_global_load_lds(GAS1(s + 64 * 128), LAS3(d + 8192), 16, 0, 0);
    };
    auto SH_B = [&](int bf, int hf, int kt) {
        const char* s = sB + (size_t)(hf * 128) * ldb + (size_t)kt * 128;
        char* d = smem + bf * BSTRIDE + 16384 + hf * 16384 + wid * 1024;
        __builtin_amdgcn_global_load_lds(GAS1(s), LAS3(d), 16, 0, 0);
        __builtin_amdgcn_global_load_lds(GAS1(s + 64 * ldb), LAS3(d + 8192), 16, 0, 0);
    };

    f32x4 acc[4][4];
    #pragma unroll
    for (int i = 0; i < 4; ++i)
        #pragma unroll
        for (int j = 0; j < 4; ++j) acc[i][j] = (f32x4){0.f, 0.f, 0.f, 0.f};
    bf16x8 bv[4];

    const int NT = 2 * m_blk + 2;          // causal BK=64 tiles (even)

    SH_A(0, 0); SH_B(0, 0, 0); SH_B(0, 1, 0);
    SH_A(1, 1); SH_B(1, 0, 1); SH_B(1, 1, 1);
    asm volatile("s_waitcnt vmcnt(6)" ::: "memory");
    __builtin_amdgcn_s_barrier();

    int cur = 0, pb = 2;
    for (int t = 0; t < NT; ++t) {
        const char* base = smem + cur * BSTRIDE;
        const int t2 = t + 2;
        const bool pf = t2 < NT;
        phase_op<0,0,-1,true>(base, offA0, offB0, bv, acc,
            [&]{ if (pf) { SH_A(pb, t2); SH_B(pb, 0, t2); } });
        phase_op<1,0, 6,true>(base, offA0, offB0, bv, acc,
            [&]{ if (pf) SH_B(pb, 1, t2); });
        cur = (cur == 2) ? 0 : cur + 1;
        pb  = (pb  == 2) ? 0 : pb  + 1;
    }

    // epilogue: gate with U and scatter to (t*4+b, h*256+hd)
    const int fq = c * 4;
    #pragma unroll
    for (int mi = 0; mi < 4; ++mi) {
        #pragma unroll
        for (int ni = 0; ni < 4; ++ni) {
            const int nn = n0 + wrn + ni * 16 + frow;   // 0..1023
            const int b  = nn >> 8, hd = nn & 255;
            #pragma unroll
            for (int j = 0; j < 4; ++j) {
                const int t = m0 + wrm + mi * 16 + fq + j;
                const size_t idx = ((size_t)t * BQ + b) * D1Q + h * HDQ + hd;
                const float uval = (float)U[idx];
                O[idx] = (bf16_t)(uval * acc[mi][ni][j]);
            }
        }
    }
}

// ---------------------------------------------------------------- launch

extern "C" void kernel_launch(void* const* d_in, const int* in_sizes, int n_in,
                              void* d_out, int out_size, void* d_ws, size_t ws_size,
                              hipStream_t stream)
{
    const float* x    = (const float*)d_in[0];
    const float* Wu   = (const float*)d_in[1];
    const float* bu   = (const float*)d_in[2];
    const float* Wv   = (const float*)d_in[3];
    const float* bv   = (const float*)d_in[4];
    const float* Wo   = (const float*)d_in[5];
    const float* bo   = (const float*)d_in[6];
    const float* zero = (const float*)d_in[7];
    const float* pos  = (const float*)d_in[8];
    float* out = (float*)d_out;

    char* ws = (char*)d_ws;
    size_t off = 0;
    auto alloc = [&](size_t bytes) {
        char* p = ws + off;
        off += (bytes + 255) & ~(size_t)255;
        return p;
    };
    bf16_t* xn     = (bf16_t*)alloc((size_t)NBQ * EQ * 2);
    bf16_t* Wub    = (bf16_t*)alloc((size_t)D1Q * EQ * 2);    // | contiguous:
    bf16_t* Wvb    = (bf16_t*)alloc((size_t)D1Q * EQ * 2);    // | B = [Wu; Wv]
    bf16_t* Wob    = (bf16_t*)alloc((size_t)EQ * D1Q * 2);
    bf16_t* Atiles = (bf16_t*)alloc((size_t)HQ * 32 * 8192 * 2);  // 4 MB
    bf16_t* Ub     = (bf16_t*)alloc((size_t)NBQ * D1Q * 2);
    bf16_t* VTb    = (bf16_t*)alloc((size_t)NBQ * D1Q * 2);   // (h,b,hd,t)
    bf16_t* Ob     = (bf16_t*)alloc((size_t)NBQ * D1Q * 2);

    convert_kernel<<<8192, 256, 0, stream>>>(Wu, Wv, Wo, Wub, Wvb, Wob);
    build_toep_tiles2<<<dim3(32, 8), 256, 0, stream>>>(zero, pos, Atiles);
    rmsnorm_kernel<<<NBQ, 256, 0, stream>>>(x, xn);

    // merged U+V: M=8192, N=4096, K=1024 — 256x256 tiles, 512 blocks, 16 waves
    dim3 g1(16, NBQ / 256);          // (16, 32) = 512 blocks
    gemm_uv<<<g1, 1024, 0, stream>>>(xn, Wub, bu, bv, Ub, VTb);

    gemm_toep4p<<<512, 512, 0, stream>>>(VTb, Atiles, Ub, Ob);

    // final: M=8192, N=1024, K=2048 — 128x256 tiles, 256 blocks, 4-phase
    dim3 g2(EQ / 256, NBQ / 128);    // (4, 64)
    gemm_fin<<<g2, 512, 0, stream>>>(Ob, Wob, bo, x, out);
}

// Round 10
// 197.963 us; speedup vs baseline: 1.0223x; 1.0223x over previous
//
#include <hip/hip_runtime.h>
#include <cstdint>
#include <cstddef>

#define LQ   2048
#define BQ   4
#define EQ   1024
#define HQ   8
#define D1Q  2048
#define HDQ  256
#define NBQ  (LQ*BQ)   // 8192 rows in (n,b) layout

typedef __bf16 bf16_t;
typedef __bf16 bf16x8 __attribute__((ext_vector_type(8)));
typedef __bf16 bf16x4 __attribute__((ext_vector_type(4)));
typedef float  f32x4  __attribute__((ext_vector_type(4)));

#define GAS1(p) ((const __attribute__((address_space(1))) void*)(p))
#define LAS3(p) ((__attribute__((address_space(3))) void*)(p))

// ---------------------------------------------------------------- utilities

__global__ __launch_bounds__(256) void convert_kernel(
    const float* __restrict__ Wu, const float* __restrict__ Wv,
    const float* __restrict__ Wo,
    bf16_t* __restrict__ Wub, bf16_t* __restrict__ Wvb,
    bf16_t* __restrict__ Wob)
{
    const size_t i = (size_t)blockIdx.x * 256 + threadIdx.x;
    if (i < (size_t)D1Q * EQ) {
        Wub[i] = (bf16_t)Wu[i];
        Wvb[i] = (bf16_t)Wv[i];
        Wob[i] = (bf16_t)Wo[i];
    }
}

// Precompute Toeplitz A-tiles, 128 rows x 64 cols (BK=64), diag offset (q-1)*64.
__global__ __launch_bounds__(256) void build_toep_tiles2(
    const float* __restrict__ zero, const float* __restrict__ pos,
    bf16_t* __restrict__ At)
{
    const int q = blockIdx.x;        // 0..31
    const int h = blockIdx.y;        // 0..7
    const int doff = (q - 1) * 64;
    const int tid = threadIdx.x;
    bf16_t* dst = At + ((size_t)h * 32 + q) * 8192;
    const int r  = tid >> 1;
    const int c0 = (tid & 1) * 32;
    bf16_t vals[32];
    #pragma unroll
    for (int j = 0; j < 32; ++j) {
        const int d = doff + r - (c0 + j);
        float v = 0.f;
        if (d == 0) v = zero[h];
        else if (d > 0 && d < LQ) v = pos[(size_t)h * (LQ - 1) + d - 1];
        vals[j] = (bf16_t)v;
    }
    #pragma unroll
    for (int qq = 0; qq < 4; ++qq)
        *(bf16x8*)(dst + r * 64 + c0 + qq * 8) = *(bf16x8*)(vals + qq * 8);
}

__global__ __launch_bounds__(256) void rmsnorm_kernel(
    const float* __restrict__ x, bf16_t* __restrict__ xn)
{
    const int row = blockIdx.x;           // 0..8191
    const int tid = threadIdx.x;
    const float4 v = ((const float4*)(x + (size_t)row * EQ))[tid];
    float ss = v.x*v.x + v.y*v.y + v.z*v.z + v.w*v.w;
    #pragma unroll
    for (int m = 32; m >= 1; m >>= 1) ss += __shfl_xor(ss, m, 64);
    __shared__ float red[4];
    const int wid = tid >> 6, lane = tid & 63;
    if (lane == 0) red[wid] = ss;
    __syncthreads();
    const float tot = red[0] + red[1] + red[2] + red[3];
    const float inv = 1.f / (sqrtf(tot * (1.f / EQ)) + 1e-8f);
    bf16x4 o;
    o[0] = (bf16_t)(v.x * inv); o[1] = (bf16_t)(v.y * inv);
    o[2] = (bf16_t)(v.z * inv); o[3] = (bf16_t)(v.w * inv);
    *(bf16x4*)(xn + (size_t)row * EQ + tid * 4) = o;
}

// ---------------------------------------------------------------- phase primitive
// {ds_read 4 av (+4 bv) ; issue stage ; barrier ; setprio+16 MFMA ;
//  optional counted vmcnt ; barrier}.  LDS rows 128 B, 8x16B slots, XOR row&7.
template<int KK, int MH, int WAITN, bool LDB, int MI_, typename F>
__device__ __forceinline__ void phase_op(const char* base, int offA0, int offB0,
    bf16x8 (&bv)[4], f32x4 (&acc)[MI_][4], F&& stage)
{
    bf16x8 av[4];
    #pragma unroll
    for (int i = 0; i < 4; ++i)
        av[i] = *(const bf16x8*)(base + (offA0 ^ (KK << 6)) + (MH * 4 + i) * 2048);
    if constexpr (LDB) {
        #pragma unroll
        for (int i = 0; i < 4; ++i)
            bv[i] = *(const bf16x8*)(base + (offB0 ^ (KK << 6)) + i * 2048);
    }
    stage();
    __builtin_amdgcn_s_barrier();
    __builtin_amdgcn_s_setprio(1);
    #pragma unroll
    for (int i = 0; i < 4; ++i)
        #pragma unroll
        for (int ni = 0; ni < 4; ++ni)
            acc[MH * 4 + i][ni] = __builtin_amdgcn_mfma_f32_16x16x32_bf16(
                av[i], bv[ni], acc[MH * 4 + i][ni], 0, 0, 0);
    __builtin_amdgcn_s_setprio(0);
    if constexpr (WAITN >= 0)
        asm volatile("s_waitcnt vmcnt(%0)" :: "i"(WAITN) : "memory");
    __builtin_amdgcn_s_barrier();
}

// ---------------------------------------------------------------- merged U+V GEMM, 8-phase
// BM=BN=256, BK=64, 8 waves (2M x 4N), wave tile 128x64, acc[8][4].
// 2 LDS buffers (128 KB).  Stage placement derived from buffer liveness so
// every load is 3-4 phases old at its wait:
//   p1: A(2i+1)->buf1   p4: B(2i+2)->buf0   p5: A(2i+2)->buf0   p8: B(2i+3)->buf1
// waits: vmcnt(4) at p4/p8 only (0 only in the tail iteration).
// B = [Wu; Wv]: bx<8 -> U (silu, row-major); bx>=8 -> V (silu, (h,b,hd,t)
// via LDS-staged per-wave transpose, full 64-B t-runs).
__global__ __launch_bounds__(512, 1) void gemm_uv8p(
    const bf16_t* __restrict__ A, const bf16_t* __restrict__ Bm,
    const float* __restrict__ bbu, const float* __restrict__ bbv,
    bf16_t* __restrict__ Ub, bf16_t* __restrict__ Vt)
{
    constexpr int K = EQ;                     // 1024
    constexpr int BSTRIDE = 65536;            // A 32K + B 32K
    __shared__ alignas(16) char smem[2 * BSTRIDE];

    // XCD-chunked bijective swizzle (nwg = 512)
    const int nwg   = gridDim.x * gridDim.y;
    const int bid0  = blockIdx.y * gridDim.x + blockIdx.x;
    const int chunkw = nwg >> 3;
    const int sb    = (bid0 & 7) * chunkw + (bid0 >> 3);
    const int bx    = sb % gridDim.x;
    const int by    = sb / gridDim.x;

    const int tid  = threadIdx.x;
    const int wid  = tid >> 6;
    const int lane = tid & 63;
    const int frow = lane & 15;
    const int c    = lane >> 4;
    const int m0 = by * 256;
    const int n0 = bx * 256;
    const int wrm = (wid >> 2) * 128;
    const int wrn = (wid & 3) * 64;

    const int g = frow & 7;
    const int offA0 = (wrm + frow) * 128 + ((c ^ g) << 4);
    const int offB0 = 32768 + (wrn + frow) * 128 + ((c ^ g) << 4);

    const int rl = tid >> 3;                  // 0..63
    const int ls = (tid & 7) ^ (rl & 7);
    const size_t lda2 = (size_t)K * 2;
    const char* sA = (const char*)A  + (size_t)(m0 + rl) * lda2 + ls * 16;
    const char* sB = (const char*)Bm + (size_t)(n0 + rl) * lda2 + ls * 16;

    // stage half-tile hf of operand op (0=A,1=B) of K-tile kt into buffer bf
    auto SH = [&](int bf, int op, int hf, int kt) {
        const char* s = (op ? sB : sA) + (size_t)(hf * 128) * lda2 + (size_t)kt * 128;
        char* d = smem + bf * BSTRIDE + op * 32768 + hf * 16384 + wid * 1024;
        __builtin_amdgcn_global_load_lds(GAS1(s), LAS3(d), 16, 0, 0);
        __builtin_amdgcn_global_load_lds(GAS1(s + 64 * lda2), LAS3(d + 8192), 16, 0, 0);
    };

    f32x4 acc[8][4];
    #pragma unroll
    for (int i = 0; i < 8; ++i)
        #pragma unroll
        for (int j = 0; j < 4; ++j) acc[i][j] = (f32x4){0.f, 0.f, 0.f, 0.f};
    bf16x8 bv[4];

    const int NT = K >> 6;                    // 16 (even)

    // prologue: tile0 fully into buf0, B(tile1) into buf1
    SH(0,0,0,0); SH(0,0,1,0); SH(0,1,0,0); SH(0,1,1,0);
    SH(1,1,0,1); SH(1,1,1,1);
    asm volatile("s_waitcnt vmcnt(4)" ::: "memory");
    __builtin_amdgcn_s_barrier();

    const char* b0 = smem;
    const char* b1 = smem + BSTRIDE;
    for (int i = 0; i < NT / 2; ++i) {
        const int t1 = 2 * i + 1, t2 = 2 * i + 2, t3 = 2 * i + 3;
        const bool s2 = t2 < NT;              // NT even => s2 == (t3 <= NT-1+1)... t3<NT iff s2
        // p1: read buf0 kk0 A0-3 + B; stage A(t1)->buf1 (age 3 at p4 wait)
        phase_op<0,0,-1,true >(b0, offA0, offB0, bv, acc,
            [&]{ SH(1,0,0,t1); SH(1,0,1,t1); });
        phase_op<0,1,-1,false>(b0, offA0, offB0, bv, acc, [&]{});
        phase_op<1,0,-1,true >(b0, offA0, offB0, bv, acc, [&]{});
        // p4: stage B(t2)->buf0 (B region free after p3); wait for t1's A+B
        if (s2) phase_op<1,1, 4,false>(b0, offA0, offB0, bv, acc,
            [&]{ SH(0,1,0,t2); SH(0,1,1,t2); });
        else    phase_op<1,1, 0,false>(b0, offA0, offB0, bv, acc, [&]{});
        // p5: read buf1 (t1); stage A(t2)->buf0 (A region free after p4)
        phase_op<0,0,-1,true >(b1, offA0, offB0, bv, acc,
            [&]{ if (s2) { SH(0,0,0,t2); SH(0,0,1,t2); } });
        phase_op<0,1,-1,false>(b1, offA0, offB0, bv, acc, [&]{});
        phase_op<1,0,-1,true >(b1, offA0, offB0, bv, acc, [&]{});
        // p8: stage B(t3)->buf1; wait for t2's A+B
        if (s2) phase_op<1,1, 4,false>(b1, offA0, offB0, bv, acc,
            [&]{ SH(1,1,0,t3); SH(1,1,1,t3); });
        else    phase_op<1,1,-1,false>(b1, offA0, offB0, bv, acc, [&]{});
    }

    if (bx < 8) {
        // U epilogue: silu(acc + bu) -> row-major (nb, d1)
        const int fq = c * 4;
        #pragma unroll
        for (int mi = 0; mi < 8; ++mi) {
            #pragma unroll
            for (int ni = 0; ni < 4; ++ni) {
                const int gn = n0 + wrn + ni * 16 + frow;
                #pragma unroll
                for (int j = 0; j < 4; ++j) {
                    const int gm = m0 + wrm + mi * 16 + fq + j;
                    float v = acc[mi][ni][j] + bbu[gn];
                    v = v / (1.f + __expf(-v));
                    Ub[(size_t)gm * D1Q + gn] = (bf16_t)v;
                }
            }
        }
        return;
    }

    // V epilogue: silu(acc + bv) -> (h, b, hd, t) via LDS transpose (R6/R8-verified)
    {
        const int n0v = n0 - 2048;
        const int hh  = n0v >> 8;
        float bb[4];
        #pragma unroll
        for (int ni = 0; ni < 4; ++ni) bb[ni] = bbv[n0v + wrn + ni * 16 + frow];

        #pragma unroll
        for (int p = 0; p < 2; ++p) {          // ni-pair halves
            __syncthreads();
            bf16_t* chunk = (bf16_t*)smem + wid * 4224;  // 32 n x [b:4][t:32], stride 132
            #pragma unroll
            for (int mi = 0; mi < 8; ++mi) {
                #pragma unroll
                for (int nio = 0; nio < 2; ++nio) {
                    const int ni = p * 2 + nio;
                    const int nl = nio * 16 + frow;
                    #pragma unroll
                    for (int j = 0; j < 4; ++j) {   // j == b
                        float v = acc[mi][ni][j] + bb[ni];
                        v = v / (1.f + __expf(-v));
                        chunk[nl * 132 + j * 32 + mi * 4 + c] = (bf16_t)v;
                    }
                }
            }
            __syncthreads();
            const int nl  = lane & 31;
            const int bh2 = lane >> 5;
            const int hd  = wrn + p * 32 + nl;
            const int t0  = (m0 + wrm) >> 2;
            #pragma unroll
            for (int bi = 0; bi < 2; ++bi) {
                const int b2 = bh2 * 2 + bi;
                const bf16_t* src = chunk + nl * 132 + b2 * 32;
                bf16_t* dst = Vt + (((size_t)hh * 4 + b2) * 256 + hd) * (size_t)LQ + t0;
                #pragma unroll
                for (int q = 0; q < 4; ++q)
                    *(bf16x8*)(dst + q * 8) = *(const bf16x8*)(src + q * 8);
            }
        }
    }
}

// ---------------------------------------------------------------- 4-phase 128x256 GEMM (final)
__global__ __launch_bounds__(512, 1) void gemm_fin(
    const bf16_t* __restrict__ A, const bf16_t* __restrict__ Bm,
    const float* __restrict__ bias, const float* __restrict__ res,
    float* __restrict__ Cf)
{
    constexpr int K = D1Q, N = EQ;
    constexpr int BSTRIDE = 49152;            // A 16K + B 32K
    __shared__ alignas(16) char smem[3 * BSTRIDE];

    const int nwg   = gridDim.x * gridDim.y;
    const int bid0  = blockIdx.y * gridDim.x + blockIdx.x;
    const int chunkw = nwg >> 3;
    const int sb    = (bid0 & 7) * chunkw + (bid0 >> 3);
    const int bx    = sb % gridDim.x;
    const int by    = sb / gridDim.x;

    const int tid  = threadIdx.x;
    const int wid  = tid >> 6;
    const int lane = tid & 63;
    const int frow = lane & 15;
    const int c    = lane >> 4;
    const int m0 = by * 128;
    const int n0 = bx * 256;
    const int wrm = (wid >> 2) * 64;
    const int wrn = (wid & 3) * 64;

    const int g = frow & 7;
    const int offA0 = (wrm + frow) * 128 + ((c ^ g) << 4);
    const int offB0 = 16384 + (wrn + frow) * 128 + ((c ^ g) << 4);

    const int rl = tid >> 3;
    const int ls = (tid & 7) ^ (rl & 7);
    const size_t lda2 = (size_t)K * 2;
    const char* sA = (const char*)A  + (size_t)(m0 + rl) * lda2 + ls * 16;
    const char* sB = (const char*)Bm + (size_t)(n0 + rl) * lda2 + ls * 16;

    auto SH_A = [&](int bf, int kt) {
        const char* s = sA + (size_t)kt * 128;
        char* d = smem + bf * BSTRIDE + wid * 1024;
        __builtin_amdgcn_global_load_lds(GAS1(s), LAS3(d), 16, 0, 0);
        __builtin_amdgcn_global_load_lds(GAS1(s + 64 * lda2), LAS3(d + 8192), 16, 0, 0);
    };
    auto SH_B = [&](int bf, int hf, int kt) {
        const char* s = sB + (size_t)(hf * 128) * lda2 + (size_t)kt * 128;
        char* d = smem + bf * BSTRIDE + 16384 + hf * 16384 + wid * 1024;
        __builtin_amdgcn_global_load_lds(GAS1(s), LAS3(d), 16, 0, 0);
        __builtin_amdgcn_global_load_lds(GAS1(s + 64 * lda2), LAS3(d + 8192), 16, 0, 0);
    };

    f32x4 acc[4][4];
    #pragma unroll
    for (int i = 0; i < 4; ++i)
        #pragma unroll
        for (int j = 0; j < 4; ++j) acc[i][j] = (f32x4){0.f, 0.f, 0.f, 0.f};
    bf16x8 bv[4];

    const int NT = K >> 6;                    // 32

    SH_A(0, 0); SH_B(0, 0, 0); SH_B(0, 1, 0);
    SH_A(1, 1); SH_B(1, 0, 1); SH_B(1, 1, 1);
    asm volatile("s_waitcnt vmcnt(6)" ::: "memory");
    __builtin_amdgcn_s_barrier();

    int cur = 0, pb = 2;
    for (int t = 0; t < NT; ++t) {
        const char* base = smem + cur * BSTRIDE;
        const int t2 = t + 2;
        const bool pf = t2 < NT;
        phase_op<0,0,-1,true>(base, offA0, offB0, bv, acc,
            [&]{ if (pf) { SH_A(pb, t2); SH_B(pb, 0, t2); } });
        phase_op<1,0, 6,true>(base, offA0, offB0, bv, acc,
            [&]{ if (pf) SH_B(pb, 1, t2); });
        cur = (cur == 2) ? 0 : cur + 1;
        pb  = (pb  == 2) ? 0 : pb  + 1;
    }

    const int fq = c * 4;
    #pragma unroll
    for (int mi = 0; mi < 4; ++mi) {
        #pragma unroll
        for (int ni = 0; ni < 4; ++ni) {
            const int gn = n0 + wrn + ni * 16 + frow;
            #pragma unroll
            for (int j = 0; j < 4; ++j) {
                const int gm = m0 + wrm + mi * 16 + fq + j;
                Cf[(size_t)gm * N + gn] =
                    acc[mi][ni][j] + bias[gn] + res[(size_t)gm * N + gn];
            }
        }
    }
}

// ---------------------------------------------------------------- 4-phase Toeplitz GEMM
__global__ __launch_bounds__(512, 1) void gemm_toep4p(
    const bf16_t* __restrict__ VT, const bf16_t* __restrict__ Atl,
    const bf16_t* __restrict__ U, bf16_t* __restrict__ O)
{
    constexpr int BSTRIDE = 49152;
    __shared__ alignas(16) char smem[3 * BSTRIDE];

    const int bid   = blockIdx.x;          // 0..511
    const int m_blk = 15 - (bid >> 5);     // heavy-first
    const int sub   = bid & 31;
    const int h     = sub >> 2;
    const int n0    = (sub & 3) * 256;
    const int m0    = m_blk * 128;

    const int tid  = threadIdx.x;
    const int wid  = tid >> 6;
    const int lane = tid & 63;
    const int frow = lane & 15;
    const int c    = lane >> 4;
    const int wrm  = (wid >> 2) * 64;
    const int wrn  = (wid & 3) * 64;

    const int g = frow & 7;
    const int offA0 = (wrm + frow) * 128 + ((c ^ g) << 4);
    const int offB0 = 16384 + (wrn + frow) * 128 + ((c ^ g) << 4);

    const int rl = tid >> 3;
    const int ls = (tid & 7) ^ (rl & 7);
    const char* Ah = (const char*)Atl + (size_t)h * 32 * 16384;
    const size_t ldb = (size_t)LQ * 2;
    const char* sB = (const char*)VT + ((size_t)h * 1024 + n0 + rl) * ldb + ls * 16;

    auto SH_A = [&](int bf, int kt) {
        const int q = 2 * m_blk - kt + 1;
        const char* s = Ah + (size_t)q * 16384 + (size_t)rl * 128 + ls * 16;
        char* d = smem + bf * BSTRIDE + wid * 1024;
        __builtin_amdgcn_global_load_lds(GAS1(s), LAS3(d), 16, 0, 0);
        __builtin_amdgcn_global_load_lds(GAS1(s + 64 * 128), LAS3(d + 8192), 16, 0, 0);
    };
    auto SH_B = [&](int bf, int hf, int kt) {
        const char* s = sB + (size_t)(hf * 128) * ldb + (size_t)kt * 128;
        char* d = smem + bf * BSTRIDE + 16384 + hf * 16384 + wid * 1024;
        __builtin_amdgcn_global_load_lds(GAS1(s), LAS3(d), 16, 0, 0);
        __builtin_amdgcn_global_load_lds(GAS1(s + 64 * ldb), LAS3(d + 8192), 16, 0, 0);
    };

    f32x4 acc[4][4];
    #pragma unroll
    for (int i = 0; i < 4; ++i)
        #pragma unroll
        for (int j = 0; j < 4; ++j) acc[i][j] = (f32x4){0.f, 0.f, 0.f, 0.f};
    bf16x8 bv[4];

    const int NT = 2 * m_blk + 2;          // causal BK=64 tiles (even)

    SH_A(0, 0); SH_B(0, 0, 0); SH_B(0, 1, 0);
    SH_A(1, 1); SH_B(1, 0, 1); SH_B(1, 1, 1);
    asm volatile("s_waitcnt vmcnt(6)" ::: "memory");
    __builtin_amdgcn_s_barrier();

    int cur = 0, pb = 2;
    for (int t = 0; t < NT; ++t) {
        const char* base = smem + cur * BSTRIDE;
        const int t2 = t + 2;
        const bool pf = t2 < NT;
        phase_op<0,0,-1,true>(base, offA0, offB0, bv, acc,
            [&]{ if (pf) { SH_A(pb, t2); SH_B(pb, 0, t2); } });
        phase_op<1,0, 6,true>(base, offA0, offB0, bv, acc,
            [&]{ if (pf) SH_B(pb, 1, t2); });
        cur = (cur == 2) ? 0 : cur + 1;
        pb  = (pb  == 2) ? 0 : pb  + 1;
    }

    // epilogue: gate with U and scatter to (t*4+b, h*256+hd)
    const int fq = c * 4;
    #pragma unroll
    for (int mi = 0; mi < 4; ++mi) {
        #pragma unroll
        for (int ni = 0; ni < 4; ++ni) {
            const int nn = n0 + wrn + ni * 16 + frow;   // 0..1023
            const int b  = nn >> 8, hd = nn & 255;
            #pragma unroll
            for (int j = 0; j < 4; ++j) {
                const int t = m0 + wrm + mi * 16 + fq + j;
                const size_t idx = ((size_t)t * BQ + b) * D1Q + h * HDQ + hd;
                const float uval = (float)U[idx];
                O[idx] = (bf16_t)(uval * acc[mi][ni][j]);
            }
        }
    }
}

// ---------------------------------------------------------------- launch

extern "C" void kernel_launch(void* const* d_in, const int* in_sizes, int n_in,
                              void* d_out, int out_size, void* d_ws, size_t ws_size,
                              hipStream_t stream)
{
    const float* x    = (const float*)d_in[0];
    const float* Wu   = (const float*)d_in[1];
    const float* bu   = (const float*)d_in[2];
    const float* Wv   = (const float*)d_in[3];
    const float* bv   = (const float*)d_in[4];
    const float* Wo   = (const float*)d_in[5];
    const float* bo   = (const float*)d_in[6];
    const float* zero = (const float*)d_in[7];
    const float* pos  = (const float*)d_in[8];
    float* out = (float*)d_out;

    char* ws = (char*)d_ws;
    size_t off = 0;
    auto alloc = [&](size_t bytes) {
        char* p = ws + off;
        off += (bytes + 255) & ~(size_t)255;
        return p;
    };
    bf16_t* xn     = (bf16_t*)alloc((size_t)NBQ * EQ * 2);
    bf16_t* Wub    = (bf16_t*)alloc((size_t)D1Q * EQ * 2);    // | contiguous:
    bf16_t* Wvb    = (bf16_t*)alloc((size_t)D1Q * EQ * 2);    // | B = [Wu; Wv]
    bf16_t* Wob    = (bf16_t*)alloc((size_t)EQ * D1Q * 2);
    bf16_t* Atiles = (bf16_t*)alloc((size_t)HQ * 32 * 8192 * 2);  // 4 MB
    bf16_t* Ub     = (bf16_t*)alloc((size_t)NBQ * D1Q * 2);
    bf16_t* VTb    = (bf16_t*)alloc((size_t)NBQ * D1Q * 2);   // (h,b,hd,t)
    bf16_t* Ob     = (bf16_t*)alloc((size_t)NBQ * D1Q * 2);

    convert_kernel<<<8192, 256, 0, stream>>>(Wu, Wv, Wo, Wub, Wvb, Wob);
    build_toep_tiles2<<<dim3(32, 8), 256, 0, stream>>>(zero, pos, Atiles);
    rmsnorm_kernel<<<NBQ, 256, 0, stream>>>(x, xn);

    // merged U+V: M=8192, N=4096, K=1024 — 256x256 tiles, 512 blocks, 8-phase
    dim3 g1(16, NBQ / 256);          // (16, 32) = 512 blocks
    gemm_uv8p<<<g1, 512, 0, stream>>>(xn, Wub, bu, bv, Ub, VTb);

    gemm_toep4p<<<512, 512, 0, stream>>>(VTb, Atiles, Ub, Ob);

    // final: M=8192, N=1024, K=2048 — 128x256 tiles, 256 blocks, 4-phase
    dim3 g2(EQ / 256, NBQ / 128);    // (4, 64)
    gemm_fin<<<g2, 512, 0, stream>>>(Ob, Wob, bo, x, out);
}